// Round 3
// baseline (170.596 us; speedup 1.0000x reference)
//
#include <hip/hip_runtime.h>
#include <math.h>

// Problem constants
#define LL 4096      // H*W
#define KK 256       // C
#define HH 64
#define WW 64
#define NHEAD 8
#define NPNT 16
#define HD 32        // C / NH

// ---------------------------------------------------------------------------
// Round-1 64x64 GEMM kept only for the tiny size projection (O=16).
// ---------------------------------------------------------------------------
template<int ATRANS, int STORE>
__global__ __launch_bounds__(256) void gemm_k(
    const float* __restrict__ A,
    const float* __restrict__ W,
    const float* __restrict__ bias,
    const float* __restrict__ p2,
    float* __restrict__ out,
    int O, int OB, int o_off)
{
    __shared__ float As[32][68];
    __shared__ float Ws[32][68];

    const int tid = threadIdx.x;
    const int b  = blockIdx.z;
    const int l0 = blockIdx.x * 64;
    const int o0 = blockIdx.y * 64;

    const int px_sub = (tid & 15) * 4;
    const int o_sub  = (tid >> 4) * 4;

    float acc[4][4] = {};

    for (int k0 = 0; k0 < KK; k0 += 32) {
        if (ATRANS == 0) {
            const int k  = tid >> 3;
            const int px = (tid & 7) * 8;
            const float* src = A + ((size_t)(b * KK + k0 + k)) * LL + l0 + px;
            float4 v0 = *(const float4*)(src);
            float4 v1 = *(const float4*)(src + 4);
            *(float4*)&As[k][px]     = v0;
            *(float4*)&As[k][px + 4] = v1;
        } else {
            const int px = tid >> 2;
            const int kq = (tid & 3) * 8;
            const float* src = A + ((size_t)(b * LL + l0 + px)) * KK + k0 + kq;
            float4 v0 = *(const float4*)(src);
            float4 v1 = *(const float4*)(src + 4);
            As[kq + 0][px] = v0.x; As[kq + 1][px] = v0.y;
            As[kq + 2][px] = v0.z; As[kq + 3][px] = v0.w;
            As[kq + 4][px] = v1.x; As[kq + 5][px] = v1.y;
            As[kq + 6][px] = v1.z; As[kq + 7][px] = v1.w;
        }
        {
            const int o  = tid >> 2;
            const int kq = (tid & 3) * 8;
            int oc = o0 + o; if (oc >= O) oc = O - 1;
            const float* src = W + (size_t)oc * KK + k0 + kq;
            float4 v0 = *(const float4*)(src);
            float4 v1 = *(const float4*)(src + 4);
            Ws[kq + 0][o] = v0.x; Ws[kq + 1][o] = v0.y;
            Ws[kq + 2][o] = v0.z; Ws[kq + 3][o] = v0.w;
            Ws[kq + 4][o] = v1.x; Ws[kq + 5][o] = v1.y;
            Ws[kq + 6][o] = v1.z; Ws[kq + 7][o] = v1.w;
        }
        __syncthreads();

        #pragma unroll
        for (int kk = 0; kk < 32; ++kk) {
            float4 a4 = *(const float4*)&As[kk][px_sub];
            float4 w4 = *(const float4*)&Ws[kk][o_sub];
            float av[4] = {a4.x, a4.y, a4.z, a4.w};
            float wv[4] = {w4.x, w4.y, w4.z, w4.w};
            #pragma unroll
            for (int i = 0; i < 4; ++i)
                #pragma unroll
                for (int j = 0; j < 4; ++j)
                    acc[i][j] += av[i] * wv[j];
        }
        __syncthreads();
    }

    #pragma unroll
    for (int i = 0; i < 4; ++i) {
        const int l = l0 + px_sub + i;
        #pragma unroll
        for (int j = 0; j < 4; ++j) {
            const int o = o0 + o_sub + j;
            if (STORE == 1) {
                out[((size_t)(b * NHEAD + (o >> 5)) * LL + l) * HD + (o & 31)] =
                    acc[i][j] + bias[o];
            } else if (STORE == 0) {
                if (o < O)
                    out[((size_t)(b * OB + o_off + o)) * LL + l] =
                        acc[i][j] + (bias ? bias[o] : 0.f);
            } else {
                const float sc = bias[o] / sqrtf(1.f + 1e-5f);
                out[((size_t)(b * OB + o)) * LL + l] = acc[i][j] * sc + p2[o];
            }
        }
    }
}

// ---------------------------------------------------------------------------
// Fused projection GEMM: 128x128 tiles, 8x8 per thread, K=256.
// blockIdx.y: 0,1 -> value_proj (-> mem2 layout); 2,3 -> anchor offsets
// (-> raw ch 16..271); 4 -> attention (-> raw ch 272..399).
// ---------------------------------------------------------------------------
__global__ __launch_bounds__(256) void proj128_k(
    const float* __restrict__ feat,
    const float* __restrict__ vw,  const float* __restrict__ vb,
    const float* __restrict__ adw, const float* __restrict__ adb,
    const float* __restrict__ atw, const float* __restrict__ atb,
    float* __restrict__ mem2, float* __restrict__ raw)
{
    __shared__ float As[32][132];
    __shared__ float Ws[32][132];

    const int tid = threadIdx.x;
    const int b  = blockIdx.z;
    const int l0 = blockIdx.x * 128;
    const int y  = blockIdx.y;

    const float* W; const float* bias; int o0w;
    if (y < 2)      { W = vw;  bias = vb;  o0w = y * 128; }
    else if (y < 4) { W = adw; bias = adb; o0w = (y - 2) * 128; }
    else            { W = atw; bias = atb; o0w = 0; }

    const int px_sub = (tid & 15) * 8;
    const int o_sub  = (tid >> 4) * 8;

    float acc[8][8] = {};

    for (int k0 = 0; k0 < KK; k0 += 32) {
        {   // A tile: feat is (B, K, L) channel-major
            const int k  = tid >> 3;          // 0..31
            const int px = (tid & 7) * 16;    // 0..112
            const float* src = feat + ((size_t)(b * KK + k0 + k)) * LL + l0 + px;
            float4 v0 = ((const float4*)src)[0];
            float4 v1 = ((const float4*)src)[1];
            float4 v2 = ((const float4*)src)[2];
            float4 v3 = ((const float4*)src)[3];
            *(float4*)&As[k][px + 0]  = v0;
            *(float4*)&As[k][px + 4]  = v1;
            *(float4*)&As[k][px + 8]  = v2;
            *(float4*)&As[k][px + 12] = v3;
        }
        {   // W tile -> transposed [k][o]
            const int o  = tid >> 1;          // 0..127
            const int kq = (tid & 1) * 16;    // 0 or 16
            const float* src = W + (size_t)(o0w + o) * KK + k0 + kq;
            float4 v0 = ((const float4*)src)[0];
            float4 v1 = ((const float4*)src)[1];
            float4 v2 = ((const float4*)src)[2];
            float4 v3 = ((const float4*)src)[3];
            Ws[kq + 0][o]  = v0.x; Ws[kq + 1][o]  = v0.y;
            Ws[kq + 2][o]  = v0.z; Ws[kq + 3][o]  = v0.w;
            Ws[kq + 4][o]  = v1.x; Ws[kq + 5][o]  = v1.y;
            Ws[kq + 6][o]  = v1.z; Ws[kq + 7][o]  = v1.w;
            Ws[kq + 8][o]  = v2.x; Ws[kq + 9][o]  = v2.y;
            Ws[kq + 10][o] = v2.z; Ws[kq + 11][o] = v2.w;
            Ws[kq + 12][o] = v3.x; Ws[kq + 13][o] = v3.y;
            Ws[kq + 14][o] = v3.z; Ws[kq + 15][o] = v3.w;
        }
        __syncthreads();

        #pragma unroll
        for (int kk = 0; kk < 32; ++kk) {
            float a[8], w[8];
            *(float4*)&a[0] = *(const float4*)&As[kk][px_sub];
            *(float4*)&a[4] = *(const float4*)&As[kk][px_sub + 4];
            *(float4*)&w[0] = *(const float4*)&Ws[kk][o_sub];
            *(float4*)&w[4] = *(const float4*)&Ws[kk][o_sub + 4];
            #pragma unroll
            for (int i = 0; i < 8; ++i)
                #pragma unroll
                for (int j = 0; j < 8; ++j)
                    acc[i][j] += a[i] * w[j];
        }
        __syncthreads();
    }

    float bj[8];
    #pragma unroll
    for (int j = 0; j < 8; ++j) bj[j] = bias[o0w + o_sub + j];

    if (y < 2) {
        const int oc = y * 128 + o_sub;       // global output channel base
        #pragma unroll
        for (int i = 0; i < 8; ++i) {
            const int l = l0 + px_sub + i;
            float* dst = mem2 + ((size_t)(b * NHEAD + (oc >> 5)) * LL + l) * HD + (oc & 31);
            float4 s0 = {acc[i][0] + bj[0], acc[i][1] + bj[1], acc[i][2] + bj[2], acc[i][3] + bj[3]};
            float4 s1 = {acc[i][4] + bj[4], acc[i][5] + bj[5], acc[i][6] + bj[6], acc[i][7] + bj[7]};
            *(float4*)dst       = s0;
            *(float4*)(dst + 4) = s1;
        }
    } else {
        // o0w already carries the 128-block offset within the projection;
        // base channel offset in raw is 16 (offsets) or 272 (attention).
        const int o_off = (y < 4) ? 16 : 272;
        #pragma unroll
        for (int j = 0; j < 8; ++j) {
            const int ch = o_off + o0w + o_sub + j;
            float* dst = raw + (size_t)(b * 400 + ch) * LL + l0 + px_sub;
            float4 s0 = {acc[0][j] + bj[j], acc[1][j] + bj[j], acc[2][j] + bj[j], acc[3][j] + bj[j]};
            float4 s1 = {acc[4][j] + bj[j], acc[5][j] + bj[j], acc[6][j] + bj[j], acc[7][j] + bj[j]};
            *(float4*)dst       = s0;
            *(float4*)(dst + 4) = s1;
        }
    }
}

// ---------------------------------------------------------------------------
// Out projection + BN: A = pre (B, L, K) pixel-major, 128x128 tiles, 8x8.
// ---------------------------------------------------------------------------
__global__ __launch_bounds__(256) void out128_k(
    const float* __restrict__ pre,
    const float* __restrict__ pw,
    const float* __restrict__ gamma,
    const float* __restrict__ beta,
    float* __restrict__ out)
{
    __shared__ float As[32][132];
    __shared__ float Ws[32][132];

    const int tid = threadIdx.x;
    const int b  = blockIdx.z;
    const int l0 = blockIdx.x * 128;
    const int o0 = blockIdx.y * 128;

    const int px_sub = (tid & 15) * 8;
    const int o_sub  = (tid >> 4) * 8;

    float acc[8][8] = {};

    for (int k0 = 0; k0 < KK; k0 += 32) {
        {   // A tile: pre is (B, L, K) pixel-major -> transpose into [k][px]
            const int px = tid >> 1;          // 0..127
            const int kq = (tid & 1) * 16;
            const float* src = pre + ((size_t)(b * LL + l0 + px)) * KK + k0 + kq;
            float4 v0 = ((const float4*)src)[0];
            float4 v1 = ((const float4*)src)[1];
            float4 v2 = ((const float4*)src)[2];
            float4 v3 = ((const float4*)src)[3];
            As[kq + 0][px]  = v0.x; As[kq + 1][px]  = v0.y;
            As[kq + 2][px]  = v0.z; As[kq + 3][px]  = v0.w;
            As[kq + 4][px]  = v1.x; As[kq + 5][px]  = v1.y;
            As[kq + 6][px]  = v1.z; As[kq + 7][px]  = v1.w;
            As[kq + 8][px]  = v2.x; As[kq + 9][px]  = v2.y;
            As[kq + 10][px] = v2.z; As[kq + 11][px] = v2.w;
            As[kq + 12][px] = v3.x; As[kq + 13][px] = v3.y;
            As[kq + 14][px] = v3.z; As[kq + 15][px] = v3.w;
        }
        {
            const int o  = tid >> 1;
            const int kq = (tid & 1) * 16;
            const float* src = pw + (size_t)(o0 + o) * KK + k0 + kq;
            float4 v0 = ((const float4*)src)[0];
            float4 v1 = ((const float4*)src)[1];
            float4 v2 = ((const float4*)src)[2];
            float4 v3 = ((const float4*)src)[3];
            Ws[kq + 0][o]  = v0.x; Ws[kq + 1][o]  = v0.y;
            Ws[kq + 2][o]  = v0.z; Ws[kq + 3][o]  = v0.w;
            Ws[kq + 4][o]  = v1.x; Ws[kq + 5][o]  = v1.y;
            Ws[kq + 6][o]  = v1.z; Ws[kq + 7][o]  = v1.w;
            Ws[kq + 8][o]  = v2.x; Ws[kq + 9][o]  = v2.y;
            Ws[kq + 10][o] = v2.z; Ws[kq + 11][o] = v2.w;
            Ws[kq + 12][o] = v3.x; Ws[kq + 13][o] = v3.y;
            Ws[kq + 14][o] = v3.z; Ws[kq + 15][o] = v3.w;
        }
        __syncthreads();

        #pragma unroll
        for (int kk = 0; kk < 32; ++kk) {
            float a[8], w[8];
            *(float4*)&a[0] = *(const float4*)&As[kk][px_sub];
            *(float4*)&a[4] = *(const float4*)&As[kk][px_sub + 4];
            *(float4*)&w[0] = *(const float4*)&Ws[kk][o_sub];
            *(float4*)&w[4] = *(const float4*)&Ws[kk][o_sub + 4];
            #pragma unroll
            for (int i = 0; i < 8; ++i)
                #pragma unroll
                for (int j = 0; j < 8; ++j)
                    acc[i][j] += a[i] * w[j];
        }
        __syncthreads();
    }

    float sc[8], be[8];
    #pragma unroll
    for (int j = 0; j < 8; ++j) {
        const int o = o0 + o_sub + j;
        sc[j] = gamma[o] / sqrtf(1.f + 1e-5f);
        be[j] = beta[o];
    }

    #pragma unroll
    for (int j = 0; j < 8; ++j) {
        const int o = o0 + o_sub + j;
        float* dst = out + (size_t)(b * KK + o) * LL + l0 + px_sub;
        float4 s0 = {acc[0][j]*sc[j]+be[j], acc[1][j]*sc[j]+be[j], acc[2][j]*sc[j]+be[j], acc[3][j]*sc[j]+be[j]};
        float4 s1 = {acc[4][j]*sc[j]+be[j], acc[5][j]*sc[j]+be[j], acc[6][j]*sc[j]+be[j], acc[7][j]*sc[j]+be[j]};
        *(float4*)dst       = s0;
        *(float4*)(dst + 4) = s1;
    }
}

// ---------------------------------------------------------------------------
// Sampling v2: block = 32 consecutive (b,h,l) groups.
// Phase 1: one task per (group, point): softmax via shfl_xor over the 16
//          point-lanes, sigmoids, bilinear weights -> 32B LDS records.
// Phase 2: 8 lanes per group, 4 channels each (float4 gathers).
// ---------------------------------------------------------------------------
__global__ __launch_bounds__(256) void sample2_k(
    const float* __restrict__ mem2,
    const float* __restrict__ raw,
    float* __restrict__ pre)
{
    __shared__ int   soff[32][17][4];
    __shared__ float swt[32][17][4];

    const int tid = threadIdx.x;

    #pragma unroll
    for (int q = 0; q < 2; ++q) {
        const int t  = q * 256 + tid;
        const int gi = t >> 4;
        const int p  = t & 15;
        const int g  = blockIdx.x * 32 + gi;
        const int l  = g & (LL - 1);
        const int h  = (g >> 12) & (NHEAD - 1);
        const int b  = g >> 15;
        const float* rb = raw + (size_t)b * 400 * LL;

        float logit = rb[(size_t)(272 + h * NPNT + p) * LL + l];
        float m = logit;
        m = fmaxf(m, __shfl_xor(m, 1));
        m = fmaxf(m, __shfl_xor(m, 2));
        m = fmaxf(m, __shfl_xor(m, 4));
        m = fmaxf(m, __shfl_xor(m, 8));
        float e = __expf(logit - m);
        float s = e;
        s += __shfl_xor(s, 1);
        s += __shfl_xor(s, 2);
        s += __shfl_xor(s, 4);
        s += __shfl_xor(s, 8);
        const float wp = e / s;

        float s0 = rb[(size_t)(h * 2 + 0) * LL + l];
        float s1 = rb[(size_t)(h * 2 + 1) * LL + l];
        s0 = fminf(fmaxf(1.f / (1.f + __expf(-s0)), 0.25f), 0.75f);
        s1 = fminf(fmaxf(1.f / (1.f + __expf(-s1)), 0.25f), 0.75f);

        float o0 = rb[(size_t)(16 + (h * NPNT + p) * 2 + 0) * LL + l];
        float o1 = rb[(size_t)(16 + (h * NPNT + p) * 2 + 1) * LL + l];
        o0 = 1.f / (1.f + __expf(-o0));
        o1 = 1.f / (1.f + __expf(-o1));

        const int xl = l & (WW - 1);
        const int yl = l >> 6;
        const float cx = ((float)xl + 0.5f) / ((float)WW + 1e-6f);
        const float cy = ((float)yl + 0.5f) / ((float)HH + 1e-6f);

        float gx = fminf(fmaxf(cx - 0.5f * s0 + o0 * s0, 0.f), 1.f);
        float gy = fminf(fmaxf(cy - 0.5f * s1 + o1 * s1, 0.f), 1.f);
        const float ix = gx * (float)(WW - 1);
        const float iy = gy * (float)(HH - 1);
        const float x0f = floorf(ix);
        const float y0f = floorf(iy);
        const float wx = ix - x0f;
        const float wy = iy - y0f;
        int x0 = min(max((int)x0f, 0), WW - 1);
        int x1 = min(x0 + 1, WW - 1);
        int y0 = min(max((int)y0f, 0), HH - 1);
        int y1 = min(y0 + 1, HH - 1);

        soff[gi][p][0] = (y0 * WW + x0) * HD;
        soff[gi][p][1] = (y0 * WW + x1) * HD;
        soff[gi][p][2] = (y1 * WW + x0) * HD;
        soff[gi][p][3] = (y1 * WW + x1) * HD;
        swt[gi][p][0] = wp * (1.f - wx) * (1.f - wy);
        swt[gi][p][1] = wp * wx * (1.f - wy);
        swt[gi][p][2] = wp * (1.f - wx) * wy;
        swt[gi][p][3] = wp * wx * wy;
    }
    __syncthreads();

    const int gi = tid >> 3;
    const int dq = (tid & 7) * 4;
    const int g  = blockIdx.x * 32 + gi;
    const int l  = g & (LL - 1);
    const int h  = (g >> 12) & (NHEAD - 1);
    const int b  = g >> 15;
    const float* mb = mem2 + (size_t)(b * NHEAD + h) * LL * HD + dq;

    float4 acc = {0.f, 0.f, 0.f, 0.f};
    #pragma unroll
    for (int p = 0; p < NPNT; ++p) {
        const int4   off = *(const int4*)&soff[gi][p][0];
        const float4 w   = *(const float4*)&swt[gi][p][0];
        const float4 g00 = *(const float4*)(mb + off.x);
        const float4 g01 = *(const float4*)(mb + off.y);
        const float4 g10 = *(const float4*)(mb + off.z);
        const float4 g11 = *(const float4*)(mb + off.w);
        acc.x += w.x * g00.x + w.y * g01.x + w.z * g10.x + w.w * g11.x;
        acc.y += w.x * g00.y + w.y * g01.y + w.z * g10.y + w.w * g11.y;
        acc.z += w.x * g00.z + w.y * g01.z + w.z * g10.z + w.w * g11.z;
        acc.w += w.x * g00.w + w.y * g01.w + w.z * g10.w + w.w * g11.w;
    }

    *(float4*)(pre + ((size_t)b * LL + l) * KK + h * HD + dq) = acc;
}

extern "C" void kernel_launch(void* const* d_in, const int* in_sizes, int n_in,
                              void* d_out, int out_size, void* d_ws, size_t ws_size,
                              hipStream_t stream) {
    const float* feat  = (const float*)d_in[0];
    const float* vw    = (const float*)d_in[1];
    const float* vb    = (const float*)d_in[2];
    const float* sw    = (const float*)d_in[3];
    const float* sb    = (const float*)d_in[4];
    const float* adw   = (const float*)d_in[5];
    const float* adb   = (const float*)d_in[6];
    const float* atw   = (const float*)d_in[7];
    const float* atb   = (const float*)d_in[8];
    const float* pw    = (const float*)d_in[9];
    const float* gamma = (const float*)d_in[10];
    const float* beta  = (const float*)d_in[11];
    float* out = (float*)d_out;
    float* ws  = (float*)d_ws;

    float* mem2 = ws;                        // B*NH*L*HD   = 2,097,152 f
    float* raw  = ws + 2097152;              // B*400*L     = 3,276,800 f
    float* pre  = raw + 3276800;             // B*L*C       = 2,097,152 f

    const dim3 blk(256);
    // value + anchor-offset + attention projections (fused, 128x128 tiles)
    proj128_k<<<dim3(32, 5, 2), blk, 0, stream>>>(feat, vw, vb, adw, adb, atw, atb, mem2, raw);
    // size projection -> raw ch [0,16)
    gemm_k<0, 0><<<dim3(64, 1, 2), blk, 0, stream>>>(feat, sw, sb, nullptr, raw, 16, 400, 0);
    // bilinear sampling + attention-weighted sum -> pre (B, L, C)
    sample2_k<<<dim3(2048), blk, 0, stream>>>(mem2, raw, pre);
    // out projection + BN -> d_out (B, C, H, W)
    out128_k<<<dim3(32, 2, 2), blk, 0, stream>>>(pre, pw, gamma, beta, out);
}

// Round 4
// 80.845 us; speedup vs baseline: 2.1102x; 2.1102x over previous
//
#include <hip/hip_runtime.h>
#include <math.h>

#define LL 4096      // H*W
#define KK 256       // C
#define HH 64
#define WW 64
#define NHEAD 8
#define NPNT 16
#define HD 32        // C / NH

typedef __attribute__((ext_vector_type(8))) short sh8;
typedef __attribute__((ext_vector_type(4))) float f32x4;

__device__ __forceinline__ unsigned short f2bf(float x) {
    union { float f; unsigned u; } v; v.f = x;
    unsigned r = v.u + 0x7FFFu + ((v.u >> 16) & 1u);
    return (unsigned short)(r >> 16);
}
__device__ __forceinline__ float bf2f(unsigned short h) {
    union { unsigned u; float f; } v; v.u = ((unsigned)h) << 16;
    return v.f;
}

// ---------------------------------------------------------------------------
// feat (B, K, L) f32  ->  featT (B*L, K) bf16 hi + lo  (pixel-major)
// 64x64 tiles via LDS.
// ---------------------------------------------------------------------------
__global__ __launch_bounds__(256) void tcvt_k(
    const float* __restrict__ feat,
    unsigned short* __restrict__ th, unsigned short* __restrict__ tl)
{
    __shared__ float T[64][68];
    const int b  = blockIdx.z;
    const int k0 = blockIdx.x * 64;
    const int l0 = blockIdx.y * 64;
    const int c  = threadIdx.x & 15;
    const int rr = threadIdx.x >> 4;

    #pragma unroll
    for (int r = 0; r < 4; ++r) {
        const int kk = rr + r * 16;
        float4 v = *(const float4*)(feat + ((size_t)(b * KK + k0 + kk)) * LL + l0 + c * 4);
        T[c * 4 + 0][kk] = v.x; T[c * 4 + 1][kk] = v.y;
        T[c * 4 + 2][kk] = v.z; T[c * 4 + 3][kk] = v.w;
    }
    __syncthreads();
    #pragma unroll
    for (int r = 0; r < 4; ++r) {
        const int ll = rr + r * 16;
        float4 v = *(const float4*)&T[ll][c * 4];
        ushort4 hi, lo;
        float x;
        x = v.x; hi.x = f2bf(x); lo.x = f2bf(x - bf2f(hi.x));
        x = v.y; hi.y = f2bf(x); lo.y = f2bf(x - bf2f(hi.y));
        x = v.z; hi.z = f2bf(x); lo.z = f2bf(x - bf2f(hi.z));
        x = v.w; hi.w = f2bf(x); lo.w = f2bf(x - bf2f(hi.w));
        const size_t off = ((size_t)(b * LL + l0 + ll)) * KK + k0 + c * 4;
        *(ushort4*)(th + off) = hi;
        *(ushort4*)(tl + off) = lo;
    }
}

// ---------------------------------------------------------------------------
// Pack weights: wcat (704, 256) = [value 256 | offset 256 | att 128 | size 16 |
// zero-pad 48] as bf16 hi/lo + bcat f32 (704). Rows 704..959: pw -> pwh/pwl.
// ---------------------------------------------------------------------------
__global__ __launch_bounds__(64) void wcvt_k(
    const float* __restrict__ vw,  const float* __restrict__ vb,
    const float* __restrict__ adw, const float* __restrict__ adb,
    const float* __restrict__ atw, const float* __restrict__ atb,
    const float* __restrict__ sw,  const float* __restrict__ sb,
    const float* __restrict__ pw,
    unsigned short* __restrict__ wh, unsigned short* __restrict__ wl,
    float* __restrict__ bcat,
    unsigned short* __restrict__ ph, unsigned short* __restrict__ pl)
{
    const int row = blockIdx.x;
    const int c   = threadIdx.x;     // 0..63, 4 elems each

    const float* src = nullptr;
    float bv = 0.f;
    unsigned short* dh; unsigned short* dl;
    int drow;

    if (row < 704) {
        const int o = row;
        if (o < 256)      { src = vw  + (size_t)o * KK;        bv = vb[o]; }
        else if (o < 512) { src = adw + (size_t)(o-256) * KK;  bv = adb[o-256]; }
        else if (o < 640) { src = atw + (size_t)(o-512) * KK;  bv = atb[o-512]; }
        else if (o < 656) { src = sw  + (size_t)(o-640) * KK;  bv = sb[o-640]; }
        dh = wh; dl = wl; drow = o;
        if (c == 0) bcat[o] = bv;
    } else {
        const int o = row - 704;
        src = pw + (size_t)o * KK;
        dh = ph; dl = pl; drow = o;
    }

    float4 v = {0.f, 0.f, 0.f, 0.f};
    if (src) v = *(const float4*)(src + c * 4);
    ushort4 hi, lo;
    float x;
    x = v.x; hi.x = f2bf(x); lo.x = f2bf(x - bf2f(hi.x));
    x = v.y; hi.y = f2bf(x); lo.y = f2bf(x - bf2f(hi.y));
    x = v.z; hi.z = f2bf(x); lo.z = f2bf(x - bf2f(hi.z));
    x = v.w; hi.w = f2bf(x); lo.w = f2bf(x - bf2f(hi.w));
    const size_t off = (size_t)drow * KK + c * 4;
    *(ushort4*)(dh + off) = hi;
    *(ushort4*)(dl + off) = lo;
}

// ---------------------------------------------------------------------------
// MFMA GEMM, split-precision bf16 (3 mfma per fragment pair), K=256.
// D[M][N] = sum_k A[m][k] * B[n][k]   (both operands row-major (x, K) bf16)
// One wave per block; wave tile 64x64 = 4x4 fragments of 16x16x32.
// EPI=0: A=featT (M=pixels), B=wcat (N=672 outputs) -> mem2 / rawp (+bias)
// EPI=1: A=pwcat (M=256 ch), B=preT (N=pixels)      -> out (BN fused)
// ---------------------------------------------------------------------------
template<int EPI>
__global__ __launch_bounds__(64) void mgemm_k(
    const unsigned short* __restrict__ Ah, const unsigned short* __restrict__ Al,
    const unsigned short* __restrict__ Bh, const unsigned short* __restrict__ Bl,
    const float* __restrict__ bias,
    const float* __restrict__ gamma, const float* __restrict__ beta,
    float* __restrict__ out0, float* __restrict__ out1)
{
    const int lam = threadIdx.x;
    const int m0 = blockIdx.x * 64;
    const int n0 = blockIdx.y * 64;
    const int row = lam & 15;
    const int kq  = (lam >> 4) * 8;

    f32x4 acc[4][4];
    #pragma unroll
    for (int i = 0; i < 4; ++i)
        #pragma unroll
        for (int j = 0; j < 4; ++j)
            acc[i][j] = (f32x4){0.f, 0.f, 0.f, 0.f};

    #pragma unroll
    for (int s = 0; s < 8; ++s) {
        const int k0 = s * 32;
        sh8 ah[4], al[4], bh[4], bl[4];
        #pragma unroll
        for (int mf = 0; mf < 4; ++mf) {
            const size_t off = ((size_t)(m0 + mf * 16 + row)) * KK + k0 + kq;
            ah[mf] = *(const sh8*)(Ah + off);
            al[mf] = *(const sh8*)(Al + off);
        }
        #pragma unroll
        for (int nf = 0; nf < 4; ++nf) {
            const size_t off = ((size_t)(n0 + nf * 16 + row)) * KK + k0 + kq;
            bh[nf] = *(const sh8*)(Bh + off);
            bl[nf] = *(const sh8*)(Bl + off);
        }
        #pragma unroll
        for (int mf = 0; mf < 4; ++mf)
            #pragma unroll
            for (int nf = 0; nf < 4; ++nf) {
                acc[mf][nf] = __builtin_amdgcn_mfma_f32_16x16x32_bf16(ah[mf], bh[nf], acc[mf][nf], 0, 0, 0);
                acc[mf][nf] = __builtin_amdgcn_mfma_f32_16x16x32_bf16(ah[mf], bl[nf], acc[mf][nf], 0, 0, 0);
                acc[mf][nf] = __builtin_amdgcn_mfma_f32_16x16x32_bf16(al[mf], bh[nf], acc[mf][nf], 0, 0, 0);
            }
    }

    if (EPI == 0) {
        float bj[4];
        #pragma unroll
        for (int nf = 0; nf < 4; ++nf) bj[nf] = bias[n0 + nf * 16 + row];
        #pragma unroll
        for (int mf = 0; mf < 4; ++mf)
            #pragma unroll
            for (int r = 0; r < 4; ++r) {
                const int m = m0 + mf * 16 + 4 * (lam >> 4) + r;   // global pixel
                const int b  = m >> 12;
                const int ll = m & (LL - 1);
                #pragma unroll
                for (int nf = 0; nf < 4; ++nf) {
                    const int o = n0 + nf * 16 + row;
                    const float v = acc[mf][nf][r] + bj[nf];
                    if (o < 256) {
                        out0[(((size_t)(b * NHEAD + (o >> 5)) * LL + ll) * HD) + (o & 31)] = v;
                    } else if (o < 640) {
                        out1[((size_t)(b * LL + ll)) * 400 + (o - 240)] = v;
                    } else if (o < 656) {
                        out1[((size_t)(b * LL + ll)) * 400 + (o - 640)] = v;
                    }
                }
            }
    } else {
        #pragma unroll
        for (int mf = 0; mf < 4; ++mf)
            #pragma unroll
            for (int r = 0; r < 4; ++r) {
                const int o = m0 + mf * 16 + 4 * (lam >> 4) + r;   // channel
                const float sc = gamma[o] / sqrtf(1.f + 1e-5f);
                const float be = beta[o];
                #pragma unroll
                for (int nf = 0; nf < 4; ++nf) {
                    const int lg = n0 + nf * 16 + row;             // global pixel
                    const int b  = lg >> 12;
                    const int ll = lg & (LL - 1);
                    out0[((size_t)(b * KK + o)) * LL + ll] = acc[mf][nf][r] * sc + be;
                }
            }
    }
}

// ---------------------------------------------------------------------------
// Sampling: phase 1 (per (group,point) task, shfl softmax) -> LDS records;
// phase 2: 8 lanes/group, float4 gathers from mem2; emits preT bf16 hi/lo.
// rawp is pixel-major: rawp[(b*L+l)*400 + c], c: 0..15 size, 16..271 offset,
// 272..399 att.
// ---------------------------------------------------------------------------
__global__ __launch_bounds__(256) void sample3_k(
    const float* __restrict__ mem2,
    const float* __restrict__ rawp,
    unsigned short* __restrict__ preH,
    unsigned short* __restrict__ preL)
{
    __shared__ int   soff[32][17][4];
    __shared__ float swt[32][17][4];

    const int tid = threadIdx.x;

    #pragma unroll
    for (int q = 0; q < 2; ++q) {
        const int t  = q * 256 + tid;
        const int gi = t >> 4;
        const int p  = t & 15;
        const int g  = blockIdx.x * 32 + gi;
        const int l  = g & (LL - 1);
        const int h  = (g >> 12) & (NHEAD - 1);
        const int b  = g >> 15;
        const float* rb = rawp + ((size_t)(b * LL + l)) * 400;

        float logit = rb[272 + h * NPNT + p];
        float m = logit;
        m = fmaxf(m, __shfl_xor(m, 1));
        m = fmaxf(m, __shfl_xor(m, 2));
        m = fmaxf(m, __shfl_xor(m, 4));
        m = fmaxf(m, __shfl_xor(m, 8));
        float e = __expf(logit - m);
        float s = e;
        s += __shfl_xor(s, 1);
        s += __shfl_xor(s, 2);
        s += __shfl_xor(s, 4);
        s += __shfl_xor(s, 8);
        const float wp = e / s;

        float s0 = rb[h * 2 + 0];
        float s1 = rb[h * 2 + 1];
        s0 = fminf(fmaxf(1.f / (1.f + __expf(-s0)), 0.25f), 0.75f);
        s1 = fminf(fmaxf(1.f / (1.f + __expf(-s1)), 0.25f), 0.75f);

        float o0 = rb[16 + (h * NPNT + p) * 2 + 0];
        float o1 = rb[16 + (h * NPNT + p) * 2 + 1];
        o0 = 1.f / (1.f + __expf(-o0));
        o1 = 1.f / (1.f + __expf(-o1));

        const int xl = l & (WW - 1);
        const int yl = l >> 6;
        const float cx = ((float)xl + 0.5f) / ((float)WW + 1e-6f);
        const float cy = ((float)yl + 0.5f) / ((float)HH + 1e-6f);

        float gx = fminf(fmaxf(cx - 0.5f * s0 + o0 * s0, 0.f), 1.f);
        float gy = fminf(fmaxf(cy - 0.5f * s1 + o1 * s1, 0.f), 1.f);
        const float ix = gx * (float)(WW - 1);
        const float iy = gy * (float)(HH - 1);
        const float x0f = floorf(ix);
        const float y0f = floorf(iy);
        const float wx = ix - x0f;
        const float wy = iy - y0f;
        int x0 = min(max((int)x0f, 0), WW - 1);
        int x1 = min(x0 + 1, WW - 1);
        int y0 = min(max((int)y0f, 0), HH - 1);
        int y1 = min(y0 + 1, HH - 1);

        soff[gi][p][0] = (y0 * WW + x0) * HD;
        soff[gi][p][1] = (y0 * WW + x1) * HD;
        soff[gi][p][2] = (y1 * WW + x0) * HD;
        soff[gi][p][3] = (y1 * WW + x1) * HD;
        swt[gi][p][0] = wp * (1.f - wx) * (1.f - wy);
        swt[gi][p][1] = wp * wx * (1.f - wy);
        swt[gi][p][2] = wp * (1.f - wx) * wy;
        swt[gi][p][3] = wp * wx * wy;
    }
    __syncthreads();

    const int gi = tid >> 3;
    const int dq = (tid & 7) * 4;
    const int g  = blockIdx.x * 32 + gi;
    const int l  = g & (LL - 1);
    const int h  = (g >> 12) & (NHEAD - 1);
    const int b  = g >> 15;
    const float* mb = mem2 + (size_t)(b * NHEAD + h) * LL * HD + dq;

    float4 acc = {0.f, 0.f, 0.f, 0.f};
    #pragma unroll
    for (int p = 0; p < NPNT; ++p) {
        const int4   off = *(const int4*)&soff[gi][p][0];
        const float4 w   = *(const float4*)&swt[gi][p][0];
        const float4 g00 = *(const float4*)(mb + off.x);
        const float4 g01 = *(const float4*)(mb + off.y);
        const float4 g10 = *(const float4*)(mb + off.z);
        const float4 g11 = *(const float4*)(mb + off.w);
        acc.x += w.x * g00.x + w.y * g01.x + w.z * g10.x + w.w * g11.x;
        acc.y += w.x * g00.y + w.y * g01.y + w.z * g10.y + w.w * g11.y;
        acc.z += w.x * g00.z + w.y * g01.z + w.z * g10.z + w.w * g11.z;
        acc.w += w.x * g00.w + w.y * g01.w + w.z * g10.w + w.w * g11.w;
    }

    ushort4 hi, lo;
    float x;
    x = acc.x; hi.x = f2bf(x); lo.x = f2bf(x - bf2f(hi.x));
    x = acc.y; hi.y = f2bf(x); lo.y = f2bf(x - bf2f(hi.y));
    x = acc.z; hi.z = f2bf(x); lo.z = f2bf(x - bf2f(hi.z));
    x = acc.w; hi.w = f2bf(x); lo.w = f2bf(x - bf2f(hi.w));
    const size_t off = ((size_t)(b * LL + l)) * KK + h * HD + dq;
    *(ushort4*)(preH + off) = hi;
    *(ushort4*)(preL + off) = lo;
}

extern "C" void kernel_launch(void* const* d_in, const int* in_sizes, int n_in,
                              void* d_out, int out_size, void* d_ws, size_t ws_size,
                              hipStream_t stream) {
    const float* feat  = (const float*)d_in[0];
    const float* vw    = (const float*)d_in[1];
    const float* vb    = (const float*)d_in[2];
    const float* sw    = (const float*)d_in[3];
    const float* sb    = (const float*)d_in[4];
    const float* adw   = (const float*)d_in[5];
    const float* adb   = (const float*)d_in[6];
    const float* atw   = (const float*)d_in[7];
    const float* atb   = (const float*)d_in[8];
    const float* pw    = (const float*)d_in[9];
    const float* gamma = (const float*)d_in[10];
    const float* beta  = (const float*)d_in[11];
    float* out = (float*)d_out;
    char* ws = (char*)d_ws;

    // workspace layout (bytes); featT region is reused for preT after proj GEMM
    unsigned short* featTh = (unsigned short*)(ws + 0);          // 4 MB
    unsigned short* featTl = (unsigned short*)(ws + 4194304);    // 4 MB
    float* mem2            = (float*)(ws + 8388608);             // 8 MB
    float* rawp            = (float*)(ws + 16777216);            // 13.1 MB
    unsigned short* wch    = (unsigned short*)(ws + 29884416);   // 352 KB
    unsigned short* wcl    = (unsigned short*)(ws + 30244864);   // 352 KB
    float* bcat            = (float*)(ws + 30605312);            // 2.8 KB
    unsigned short* pwh    = (unsigned short*)(ws + 30608128);   // 128 KB
    unsigned short* pwl    = (unsigned short*)(ws + 30739200);   // 128 KB
    unsigned short* preH   = featTh;                             // alias (safe: after proj)
    unsigned short* preL   = featTl;

    // feat -> pixel-major bf16 hi/lo
    tcvt_k<<<dim3(4, 64, 2), dim3(256), 0, stream>>>(feat, featTh, featTl);
    // weights -> concatenated bf16 hi/lo (+ bias cat) and out_proj hi/lo
    wcvt_k<<<dim3(960), dim3(64), 0, stream>>>(vw, vb, adw, adb, atw, atb, sw, sb, pw,
                                               wch, wcl, bcat, pwh, pwl);
    // all projections (value/offset/att/size) in one MFMA GEMM
    mgemm_k<0><<<dim3(128, 11), dim3(64), 0, stream>>>(featTh, featTl, wch, wcl, bcat,
                                                       nullptr, nullptr, mem2, rawp);
    // sampling -> preT bf16 hi/lo (reuses featT region)
    sample3_k<<<dim3(2048), dim3(256), 0, stream>>>(mem2, rawp, preH, preL);
    // out projection + BN
    mgemm_k<1><<<dim3(4, 128), dim3(64), 0, stream>>>(pwh, pwl, preH, preL, nullptr,
                                                      gamma, beta, out, nullptr);
}

// Round 5
// 70.340 us; speedup vs baseline: 2.4253x; 1.1494x over previous
//
#include <hip/hip_runtime.h>
#include <math.h>

#define LL 4096      // H*W
#define KK 256       // C
#define HH 64
#define WW 64
#define NHEAD 8
#define NPNT 16
#define HD 32        // C / NH

typedef unsigned short u16;
typedef __attribute__((ext_vector_type(8))) short sh8;
typedef __attribute__((ext_vector_type(4))) float f32x4;

__device__ __forceinline__ u16 f2bf(float x) {
    union { float f; unsigned u; } v; v.f = x;
    unsigned r = v.u + 0x7FFFu + ((v.u >> 16) & 1u);
    return (u16)(r >> 16);
}
__device__ __forceinline__ float bf2f(u16 h) {
    union { unsigned u; float f; } v; v.u = ((unsigned)h) << 16;
    return v.f;
}

// ---------------------------------------------------------------------------
// prep_k: fused input conversion.
// Blocks [0,512): feat (B,K,L) f32 -> featT (B*L, K) bf16 hi/lo (LDS transpose)
// Blocks [512,752): weight rows -> wcat hi/lo (+bias cat) and pw hi/lo.
//   wcat rows: [0,256) value | [256,512) offset | [512,640) att |
//              [640,656) size | [656,704) zero-pad.
// ---------------------------------------------------------------------------
__global__ __launch_bounds__(256) void prep_k(
    const float* __restrict__ feat,
    const float* __restrict__ vw,  const float* __restrict__ vb,
    const float* __restrict__ adw, const float* __restrict__ adb,
    const float* __restrict__ atw, const float* __restrict__ atb,
    const float* __restrict__ sw,  const float* __restrict__ sb,
    const float* __restrict__ pw,
    u16* __restrict__ th, u16* __restrict__ tl,
    u16* __restrict__ wh, u16* __restrict__ wl,
    float* __restrict__ bcat,
    u16* __restrict__ ph, u16* __restrict__ pl)
{
    __shared__ float T[64][68];
    const int bx = blockIdx.x;

    if (bx < 512) {
        const int b  = bx >> 8;
        const int k0 = (bx & 3) * 64;
        const int l0 = ((bx >> 2) & 63) * 64;
        const int c  = threadIdx.x & 15;
        const int rr = threadIdx.x >> 4;

        #pragma unroll
        for (int r = 0; r < 4; ++r) {
            const int kk = rr + r * 16;
            float4 v = *(const float4*)(feat + ((size_t)(b * KK + k0 + kk)) * LL + l0 + c * 4);
            T[c * 4 + 0][kk] = v.x; T[c * 4 + 1][kk] = v.y;
            T[c * 4 + 2][kk] = v.z; T[c * 4 + 3][kk] = v.w;
        }
        __syncthreads();
        #pragma unroll
        for (int r = 0; r < 4; ++r) {
            const int ll = rr + r * 16;
            float4 v = *(const float4*)&T[ll][c * 4];
            ushort4 hi, lo;
            float x;
            x = v.x; hi.x = f2bf(x); lo.x = f2bf(x - bf2f(hi.x));
            x = v.y; hi.y = f2bf(x); lo.y = f2bf(x - bf2f(hi.y));
            x = v.z; hi.z = f2bf(x); lo.z = f2bf(x - bf2f(hi.z));
            x = v.w; hi.w = f2bf(x); lo.w = f2bf(x - bf2f(hi.w));
            const size_t off = ((size_t)(b * LL + l0 + ll)) * KK + k0 + c * 4;
            *(ushort4*)(th + off) = hi;
            *(ushort4*)(tl + off) = lo;
        }
    } else {
        const int row = (bx - 512) * 4 + (threadIdx.x >> 6);  // 0..959
        const int c   = threadIdx.x & 63;

        const float* src = nullptr;
        float bv = 0.f;
        u16* dh; u16* dl;
        int drow;

        if (row < 704) {
            const int o = row;
            if (o < 256)      { src = vw  + (size_t)o * KK;        bv = vb[o]; }
            else if (o < 512) { src = adw + (size_t)(o-256) * KK;  bv = adb[o-256]; }
            else if (o < 640) { src = atw + (size_t)(o-512) * KK;  bv = atb[o-512]; }
            else if (o < 656) { src = sw  + (size_t)(o-640) * KK;  bv = sb[o-640]; }
            dh = wh; dl = wl; drow = o;
            if (c == 0) bcat[o] = bv;
        } else {
            const int o = row - 704;
            src = pw + (size_t)o * KK;
            dh = ph; dl = pl; drow = o;
        }

        float4 v = {0.f, 0.f, 0.f, 0.f};
        if (src) v = *(const float4*)(src + c * 4);
        ushort4 hi, lo;
        float x;
        x = v.x; hi.x = f2bf(x); lo.x = f2bf(x - bf2f(hi.x));
        x = v.y; hi.y = f2bf(x); lo.y = f2bf(x - bf2f(hi.y));
        x = v.z; hi.z = f2bf(x); lo.z = f2bf(x - bf2f(hi.z));
        x = v.w; hi.w = f2bf(x); lo.w = f2bf(x - bf2f(hi.w));
        const size_t off = (size_t)drow * KK + c * 4;
        *(ushort4*)(dh + off) = hi;
        *(ushort4*)(dl + off) = lo;
    }
}

// ---------------------------------------------------------------------------
// Projection MFMA GEMM: A=featT (M=8192 pixels), B=wcat (N=704), K=256.
// blockIdx.y < 4 (value cols, o<256): 1 MFMA (hi*hi), bf16 store -> mem2.
// else: split-precision 3-MFMA, f32 store -> rawp (pixel-major, 400 ch).
// One wave per block; 64x64 wave tile = 4x4 fragments of 16x16x32.
// ---------------------------------------------------------------------------
__global__ __launch_bounds__(64) void mgemm0_k(
    const u16* __restrict__ Ah, const u16* __restrict__ Al,
    const u16* __restrict__ Bh, const u16* __restrict__ Bl,
    const float* __restrict__ bias,
    u16* __restrict__ mem2, float* __restrict__ rawp)
{
    const int lam = threadIdx.x;
    const int m0 = blockIdx.x * 64;
    const int n0 = blockIdx.y * 64;
    const bool VAL = (blockIdx.y < 4);
    const int row = lam & 15;
    const int kq  = (lam >> 4) * 8;

    f32x4 acc[4][4];
    #pragma unroll
    for (int i = 0; i < 4; ++i)
        #pragma unroll
        for (int j = 0; j < 4; ++j)
            acc[i][j] = (f32x4){0.f, 0.f, 0.f, 0.f};

    #pragma unroll
    for (int s = 0; s < 8; ++s) {
        const int k0 = s * 32;
        sh8 ah[4], bh[4];
        #pragma unroll
        for (int mf = 0; mf < 4; ++mf)
            ah[mf] = *(const sh8*)(Ah + ((size_t)(m0 + mf * 16 + row)) * KK + k0 + kq);
        #pragma unroll
        for (int nf = 0; nf < 4; ++nf)
            bh[nf] = *(const sh8*)(Bh + ((size_t)(n0 + nf * 16 + row)) * KK + k0 + kq);

        if (VAL) {
            #pragma unroll
            for (int mf = 0; mf < 4; ++mf)
                #pragma unroll
                for (int nf = 0; nf < 4; ++nf)
                    acc[mf][nf] = __builtin_amdgcn_mfma_f32_16x16x32_bf16(ah[mf], bh[nf], acc[mf][nf], 0, 0, 0);
        } else {
            sh8 al[4], bl[4];
            #pragma unroll
            for (int mf = 0; mf < 4; ++mf)
                al[mf] = *(const sh8*)(Al + ((size_t)(m0 + mf * 16 + row)) * KK + k0 + kq);
            #pragma unroll
            for (int nf = 0; nf < 4; ++nf)
                bl[nf] = *(const sh8*)(Bl + ((size_t)(n0 + nf * 16 + row)) * KK + k0 + kq);
            #pragma unroll
            for (int mf = 0; mf < 4; ++mf)
                #pragma unroll
                for (int nf = 0; nf < 4; ++nf) {
                    acc[mf][nf] = __builtin_amdgcn_mfma_f32_16x16x32_bf16(ah[mf], bh[nf], acc[mf][nf], 0, 0, 0);
                    acc[mf][nf] = __builtin_amdgcn_mfma_f32_16x16x32_bf16(ah[mf], bl[nf], acc[mf][nf], 0, 0, 0);
                    acc[mf][nf] = __builtin_amdgcn_mfma_f32_16x16x32_bf16(al[mf], bh[nf], acc[mf][nf], 0, 0, 0);
                }
        }
    }

    float bj[4];
    #pragma unroll
    for (int nf = 0; nf < 4; ++nf) bj[nf] = bias[n0 + nf * 16 + row];

    #pragma unroll
    for (int mf = 0; mf < 4; ++mf)
        #pragma unroll
        for (int r = 0; r < 4; ++r) {
            const int m = m0 + mf * 16 + 4 * (lam >> 4) + r;   // global pixel
            const int b  = m >> 12;
            const int ll = m & (LL - 1);
            #pragma unroll
            for (int nf = 0; nf < 4; ++nf) {
                const int o = n0 + nf * 16 + row;
                const float v = acc[mf][nf][r] + bj[nf];
                if (VAL) {
                    mem2[(((size_t)(b * NHEAD + (o >> 5)) * LL + ll) * HD) + (o & 31)] = f2bf(v);
                } else if (o < 640) {
                    rawp[((size_t)(b * LL + ll)) * 400 + (o - 240)] = v;   // offset/att: ch 16..399
                } else if (o < 656) {
                    rawp[((size_t)(b * LL + ll)) * 400 + (o - 640)] = v;   // size: ch 0..15
                }
            }
        }
}

// ---------------------------------------------------------------------------
// Out projection + BN: A = pw hi/lo (M=256 ch), B = preT bf16 single
// (N=8192 pixels), 2 MFMAs per fragment pair.
// ---------------------------------------------------------------------------
__global__ __launch_bounds__(64) void mgemm1_k(
    const u16* __restrict__ Ah, const u16* __restrict__ Al,
    const u16* __restrict__ Bh,
    const float* __restrict__ gamma, const float* __restrict__ beta,
    float* __restrict__ out)
{
    const int lam = threadIdx.x;
    const int m0 = blockIdx.x * 64;
    const int n0 = blockIdx.y * 64;
    const int row = lam & 15;
    const int kq  = (lam >> 4) * 8;

    f32x4 acc[4][4];
    #pragma unroll
    for (int i = 0; i < 4; ++i)
        #pragma unroll
        for (int j = 0; j < 4; ++j)
            acc[i][j] = (f32x4){0.f, 0.f, 0.f, 0.f};

    #pragma unroll
    for (int s = 0; s < 8; ++s) {
        const int k0 = s * 32;
        sh8 ah[4], al[4], bh[4];
        #pragma unroll
        for (int mf = 0; mf < 4; ++mf) {
            const size_t off = ((size_t)(m0 + mf * 16 + row)) * KK + k0 + kq;
            ah[mf] = *(const sh8*)(Ah + off);
            al[mf] = *(const sh8*)(Al + off);
        }
        #pragma unroll
        for (int nf = 0; nf < 4; ++nf)
            bh[nf] = *(const sh8*)(Bh + ((size_t)(n0 + nf * 16 + row)) * KK + k0 + kq);
        #pragma unroll
        for (int mf = 0; mf < 4; ++mf)
            #pragma unroll
            for (int nf = 0; nf < 4; ++nf) {
                acc[mf][nf] = __builtin_amdgcn_mfma_f32_16x16x32_bf16(ah[mf], bh[nf], acc[mf][nf], 0, 0, 0);
                acc[mf][nf] = __builtin_amdgcn_mfma_f32_16x16x32_bf16(al[mf], bh[nf], acc[mf][nf], 0, 0, 0);
            }
    }

    #pragma unroll
    for (int mf = 0; mf < 4; ++mf)
        #pragma unroll
        for (int r = 0; r < 4; ++r) {
            const int o = m0 + mf * 16 + 4 * (lam >> 4) + r;   // channel
            const float sc = gamma[o] / sqrtf(1.f + 1e-5f);
            const float be = beta[o];
            #pragma unroll
            for (int nf = 0; nf < 4; ++nf) {
                const int lg = n0 + nf * 16 + row;             // global pixel
                const int b  = lg >> 12;
                const int ll = lg & (LL - 1);
                out[((size_t)(b * KK + o)) * LL + ll] = acc[mf][nf][r] * sc + be;
            }
        }
}

// ---------------------------------------------------------------------------
// Sampling: phase 1 (per (group,point) task, shfl softmax) -> LDS records;
// phase 2: 8 lanes/group, ushort4 bf16 gathers from mem2; emits preT bf16.
// rawp pixel-major: c 0..15 size, 16..271 offset, 272..399 att.
// ---------------------------------------------------------------------------
__global__ __launch_bounds__(256) void sample4_k(
    const u16* __restrict__ mem2,
    const float* __restrict__ rawp,
    u16* __restrict__ preH)
{
    __shared__ int   soff[32][17][4];
    __shared__ float swt[32][17][4];

    const int tid = threadIdx.x;

    #pragma unroll
    for (int q = 0; q < 2; ++q) {
        const int t  = q * 256 + tid;
        const int gi = t >> 4;
        const int p  = t & 15;
        const int g  = blockIdx.x * 32 + gi;
        const int l  = g & (LL - 1);
        const int h  = (g >> 12) & (NHEAD - 1);
        const int b  = g >> 15;
        const float* rb = rawp + ((size_t)(b * LL + l)) * 400;

        float logit = rb[272 + h * NPNT + p];
        float m = logit;
        m = fmaxf(m, __shfl_xor(m, 1));
        m = fmaxf(m, __shfl_xor(m, 2));
        m = fmaxf(m, __shfl_xor(m, 4));
        m = fmaxf(m, __shfl_xor(m, 8));
        float e = __expf(logit - m);
        float s = e;
        s += __shfl_xor(s, 1);
        s += __shfl_xor(s, 2);
        s += __shfl_xor(s, 4);
        s += __shfl_xor(s, 8);
        const float wp = e / s;

        float s0 = rb[h * 2 + 0];
        float s1 = rb[h * 2 + 1];
        s0 = fminf(fmaxf(1.f / (1.f + __expf(-s0)), 0.25f), 0.75f);
        s1 = fminf(fmaxf(1.f / (1.f + __expf(-s1)), 0.25f), 0.75f);

        float o0 = rb[16 + (h * NPNT + p) * 2 + 0];
        float o1 = rb[16 + (h * NPNT + p) * 2 + 1];
        o0 = 1.f / (1.f + __expf(-o0));
        o1 = 1.f / (1.f + __expf(-o1));

        const int xl = l & (WW - 1);
        const int yl = l >> 6;
        const float cx = ((float)xl + 0.5f) / ((float)WW + 1e-6f);
        const float cy = ((float)yl + 0.5f) / ((float)HH + 1e-6f);

        float gx = fminf(fmaxf(cx - 0.5f * s0 + o0 * s0, 0.f), 1.f);
        float gy = fminf(fmaxf(cy - 0.5f * s1 + o1 * s1, 0.f), 1.f);
        const float ix = gx * (float)(WW - 1);
        const float iy = gy * (float)(HH - 1);
        const float x0f = floorf(ix);
        const float y0f = floorf(iy);
        const float wx = ix - x0f;
        const float wy = iy - y0f;
        int x0 = min(max((int)x0f, 0), WW - 1);
        int x1 = min(x0 + 1, WW - 1);
        int y0 = min(max((int)y0f, 0), HH - 1);
        int y1 = min(y0 + 1, HH - 1);

        soff[gi][p][0] = (y0 * WW + x0) * HD;
        soff[gi][p][1] = (y0 * WW + x1) * HD;
        soff[gi][p][2] = (y1 * WW + x0) * HD;
        soff[gi][p][3] = (y1 * WW + x1) * HD;
        swt[gi][p][0] = wp * (1.f - wx) * (1.f - wy);
        swt[gi][p][1] = wp * wx * (1.f - wy);
        swt[gi][p][2] = wp * (1.f - wx) * wy;
        swt[gi][p][3] = wp * wx * wy;
    }
    __syncthreads();

    const int gi = tid >> 3;
    const int dq = (tid & 7) * 4;
    const int g  = blockIdx.x * 32 + gi;
    const int l  = g & (LL - 1);
    const int h  = (g >> 12) & (NHEAD - 1);
    const int b  = g >> 15;
    const u16* mb = mem2 + (size_t)(b * NHEAD + h) * LL * HD + dq;

    float4 acc = {0.f, 0.f, 0.f, 0.f};
    #pragma unroll
    for (int p = 0; p < NPNT; ++p) {
        const int4   off = *(const int4*)&soff[gi][p][0];
        const float4 w   = *(const float4*)&swt[gi][p][0];
        const ushort4 q00 = *(const ushort4*)(mb + off.x);
        const ushort4 q01 = *(const ushort4*)(mb + off.y);
        const ushort4 q10 = *(const ushort4*)(mb + off.z);
        const ushort4 q11 = *(const ushort4*)(mb + off.w);
        acc.x += w.x * bf2f(q00.x) + w.y * bf2f(q01.x) + w.z * bf2f(q10.x) + w.w * bf2f(q11.x);
        acc.y += w.x * bf2f(q00.y) + w.y * bf2f(q01.y) + w.z * bf2f(q10.y) + w.w * bf2f(q11.y);
        acc.z += w.x * bf2f(q00.z) + w.y * bf2f(q01.z) + w.z * bf2f(q10.z) + w.w * bf2f(q11.z);
        acc.w += w.x * bf2f(q00.w) + w.y * bf2f(q01.w) + w.z * bf2f(q10.w) + w.w * bf2f(q11.w);
    }

    ushort4 hi;
    hi.x = f2bf(acc.x); hi.y = f2bf(acc.y); hi.z = f2bf(acc.z); hi.w = f2bf(acc.w);
    *(ushort4*)(preH + ((size_t)(b * LL + l)) * KK + h * HD + dq) = hi;
}

extern "C" void kernel_launch(void* const* d_in, const int* in_sizes, int n_in,
                              void* d_out, int out_size, void* d_ws, size_t ws_size,
                              hipStream_t stream) {
    const float* feat  = (const float*)d_in[0];
    const float* vw    = (const float*)d_in[1];
    const float* vb    = (const float*)d_in[2];
    const float* sw    = (const float*)d_in[3];
    const float* sb    = (const float*)d_in[4];
    const float* adw   = (const float*)d_in[5];
    const float* adb   = (const float*)d_in[6];
    const float* atw   = (const float*)d_in[7];
    const float* atb   = (const float*)d_in[8];
    const float* pw    = (const float*)d_in[9];
    const float* gamma = (const float*)d_in[10];
    const float* beta  = (const float*)d_in[11];
    float* out = (float*)d_out;
    char* ws = (char*)d_ws;

    // workspace layout (bytes); featT region is reused for preT after proj GEMM
    u16* featTh = (u16*)(ws + 0);          // 4 MB
    u16* featTl = (u16*)(ws + 4194304);    // 4 MB
    u16* mem2   = (u16*)(ws + 8388608);    // 4 MB (bf16)
    float* rawp = (float*)(ws + 12582912); // 13.1 MB
    u16* wch    = (u16*)(ws + 25690112);   // 352 KB
    u16* wcl    = (u16*)(ws + 26050560);   // 352 KB
    float* bcat = (float*)(ws + 26411008); // 2.8 KB
    u16* pwh    = (u16*)(ws + 26413824);   // 128 KB
    u16* pwl    = (u16*)(ws + 26544896);   // 128 KB
    u16* preH   = featTh;                  // alias (featT consumed before sampling)

    // input conversions (feat transpose + all weights), one launch
    prep_k<<<dim3(752), dim3(256), 0, stream>>>(feat, vw, vb, adw, adb, atw, atb,
                                                sw, sb, pw, featTh, featTl,
                                                wch, wcl, bcat, pwh, pwl);
    // all projections; value cols 1-MFMA -> bf16 mem2, rest 3-MFMA -> rawp
    mgemm0_k<<<dim3(128, 11), dim3(64), 0, stream>>>(featTh, featTl, wch, wcl, bcat,
                                                     mem2, rawp);
    // sampling -> preT bf16 (reuses featTh region)
    sample4_k<<<dim3(2048), dim3(256), 0, stream>>>(mem2, rawp, preH);
    // out projection + BN (pw split x pre single = 2 MFMAs)
    mgemm1_k<<<dim3(4, 128), dim3(64), 0, stream>>>(pwh, pwl, preH, gamma, beta, out);
}